// Round 11
// baseline (2525.366 us; speedup 1.0000x reference)
//
#include <hip/hip_runtime.h>
#include <hip/hip_bf16.h>

#define LAT 128
#define H 256
#define OUTD 64
#define SEQ 512

typedef short bf16x8 __attribute__((ext_vector_type(8)));
typedef float f32x4  __attribute__((ext_vector_type(4)));
typedef unsigned long long u64;
typedef unsigned u32;

__device__ __forceinline__ float sigm(float x)  { return 1.f / (1.f + __expf(-x)); }
__device__ __forceinline__ float tanhf_(float x){ return 1.f - 2.f / (__expf(2.f * x) + 1.f); }

__device__ __forceinline__ short f2bs(float x) {
    __hip_bfloat16 b = __float2bfloat16(x);
    return *reinterpret_cast<short*>(&b);
}
__device__ __forceinline__ float bs2f(unsigned short h) {
    u32 b = ((u32)h) << 16;
    float f; __builtin_memcpy(&f, &b, 4); return f;
}
__device__ __forceinline__ u32 f2pair(float a, float b) {
    return ((u32)(unsigned short)f2bs(b) << 16) | (u32)(unsigned short)f2bs(a);
}
__device__ __forceinline__ bf16x8 pack8(const float* s) {
    bf16x8 v;
    v[0]=f2bs(s[0]); v[1]=f2bs(s[1]); v[2]=f2bs(s[2]); v[3]=f2bs(s[3]);
    v[4]=f2bs(s[4]); v[5]=f2bs(s[5]); v[6]=f2bs(s[6]); v[7]=f2bs(s[7]);
    return v;
}

// ---- Transport: AGENT scope, R5-proven protocol/slots/tags.
// R11 theory: with 1 wave/SIMD (R5 geometry) every poll stall idles its SIMD
// (MfmaUtil 6 + VALUBusy 19 => ~75% stall, invariant across 10 experiments).
// This round splits the two pipelines across wave groups in a 512-thread wg
// (2 waves/SIMD): group 0 = h0/L0 pipeline, group 1 = h1/L1/out pipeline.
// Each SIMD co-schedules one wave of each -> one pipeline's exposed poll
// latency hides under the other's MFMA/VALU work. Single barrier/iteration.
__device__ __forceinline__ u64 sys_load_u64(const u64* p) {
    return __hip_atomic_load((u64*)p, __ATOMIC_RELAXED, __HIP_MEMORY_SCOPE_AGENT);
}
__device__ __forceinline__ void sys_store_u64(u64* p, u64 v) {
    __hip_atomic_store(p, v, __ATOMIC_RELAXED, __HIP_MEMORY_SCOPE_AGENT);
}

// ---------------- Prologue 1: tagged h-init, c-init, L1 bias ----
__global__ void lstm_prologue_init(const float* __restrict__ z,
                                   const float* __restrict__ Whid,
                                   const float* __restrict__ bhid,
                                   const float* __restrict__ Wcell,
                                   const float* __restrict__ bcell,
                                   const float* __restrict__ bih1,
                                   const float* __restrict__ bhh1,
                                   u64* __restrict__ h0B1,
                                   u64* __restrict__ h1B1,
                                   float* __restrict__ c0,
                                   float* __restrict__ c1,
                                   float* __restrict__ gxb1)
{
    int t = blockIdx.x * 256 + threadIdx.x;
    if (t < 65536) {                     // tagged hidden-init: 2 layers x 256 b x 128 pairs
        int layer = t >> 15;
        int tt = t & 32767;
        int b = tt >> 7, cp = tt & 127;
        int colA = layer * H + 2 * cp;
        const float* zr = z + b * LAT;
        const float* wA = Whid + colA * LAT;
        const float* wB = wA + LAT;
        float a0 = bhid[colA], a1 = bhid[colA + 1];
        for (int k = 0; k < LAT; k++) { float zv = zr[k]; a0 += zv * wA[k]; a1 += zv * wB[k]; }
        u64 v = ((u64)(u32)layer << 32) | (u64)f2pair(a0, a1);
        (layer ? h1B1 : h0B1)[b * 128 + cp] = v;
    } else if (t < 196608) {             // cell init: [256 x 512]
        int tt = t - 65536;
        int b = tt >> 9, col = tt & 511;
        const float* w  = Wcell + col * LAT;
        const float* zr = z + b * LAT;
        float acc = bcell[col];
        for (int k = 0; k < LAT; k++) acc += zr[k] * w[k];
        if (col < H) c0[b * H + col] = acc;
        else         c1[b * H + (col - H)] = acc;
    } else if (t < 197632) {             // layer-1 gate bias vector [1024]
        int g = t - 196608;
        gxb1[g] = bih1[g] + bhh1[g];
    }
}

// ---------------- Prologue 2: gx0 packed bf16 pairs ----
__global__ void lstm_prologue_gx0(const float* __restrict__ z,
                                  const float* __restrict__ Win,
                                  const float* __restrict__ bin,
                                  const float* __restrict__ Wih0,
                                  const float* __restrict__ bih0,
                                  const float* __restrict__ bhh0,
                                  u32* __restrict__ gxb0u)
{
    __shared__ float xs[H];
    const int b = blockIdx.y;
    const int tid = threadIdx.x;
    {
        const float* w  = Win + tid * LAT;
        const float* zr = z + b * LAT;
        float acc = bin[tid];
        for (int k = 0; k < LAT; k++) acc += zr[k] * w[k];
        xs[tid] = acc;
    }
    __syncthreads();
    const int cA = blockIdx.x * 512 + 2 * tid;
    const float* wA = Wih0 + cA * H;
    const float* wB = wA + H;
    float a0 = bih0[cA]     + bhh0[cA];
    float a1 = bih0[cA + 1] + bhh0[cA + 1];
    for (int k = 0; k < H; k++) { float xv = xs[k]; a0 += xv * wA[k]; a1 += xv * wB[k]; }
    gxb0u[b * 512 + blockIdx.x * 256 + tid] = f2pair(a0, a1);
}

// ---------------- Persistent kernel (wave-specialized) ----------------
// 256 wgs x 512 thr (8 waves, 2/SIMD). Cluster bg = wg>>4, wg j = wg&15.
// grp = tid>>8: grp0 (waves 0-3) = h0/L0 pipeline, grp1 (waves 4-7) =
// h1/L1/out pipeline. Each group's 256 threads use the R5 thread maps
// (staging slots i*256+gt, pubslot, frag reads) verbatim.
// Per iteration k:
//   phase A: grp0 stages h0 tag k -> hs0[par]; grp1 stages h1 tag k -> hs1[par]
//   __syncthreads()  (single barrier; plane safety: reads of plane p at k
//     precede B(k+1) which precedes writes to p at k+2)
//   phase B: grp0: L0(k) from hs0, publish C0 tag k+1, prefetch C0.
//            grp1: L1(k-1) from hs0+hs1, publish C1 tag k+1, out(k-2),
//                  prefetch C1.
// Tags (tag k = h(k-1) data), parity buffers, spin guards: R5 verbatim.
__global__ __launch_bounds__(512, 2)
void lstm_persistent(const u32* __restrict__ gxb0u, const float* __restrict__ gxb1,
                     const float* __restrict__ c0g, const float* __restrict__ c1g,
                     u64* __restrict__ h0B0, u64* __restrict__ h0B1,
                     u64* __restrict__ h1B0, u64* __restrict__ h1B1,
                     const float* __restrict__ Whh0, const float* __restrict__ Wih1,
                     const float* __restrict__ Whh1, const float* __restrict__ Wout,
                     const float* __restrict__ bout, float* __restrict__ out)
{
    const int wg = blockIdx.x;
    const int bg = wg >> 4;
    const int j  = wg & 15;
    const int tid = threadIdx.x;          // 0..511
    const int grp = tid >> 8;             // 0: h0/L0, 1: h1/L1/out
    const int gt  = tid & 255;
    const int gwave = gt >> 6;
    const int q  = (gt >> 4) & 3;
    const int ln = gt & 15;
    const int mycol = j * 16 + gwave * 4 + q;
    const int myb   = bg * 16 + ln;

    __shared__ u32 hs0[2][16 * 132];      // parity planes, row-major packed pairs
    __shared__ u32 hs1[2][16 * 132];

    // ---- A-frags per group (m = c*4 + g packing, R5 map) ----
    bf16x8 wfA[8], wfB[8], wo[8];
    {
        const int arow = (ln & 3) * H + j * 16 + gwave * 4 + (ln >> 2);
        if (grp == 0) {
            const float* s = Whh0 + arow * H;
            #pragma unroll
            for (int kk = 0; kk < 8; kk++) wfA[kk] = pack8(s + kk * 32 + q * 8);
        } else {
            const float* s1 = Wih1 + arow * H;
            const float* s2 = Whh1 + arow * H;
            #pragma unroll
            for (int kk = 0; kk < 8; kk++) {
                wfA[kk] = pack8(s1 + kk * 32 + q * 8);
                wfB[kk] = pack8(s2 + kk * 32 + q * 8);
            }
        }
    }
    const bool doOut = (grp == 1) && (j < 4) && (gwave == 0);
    float bor[4] = {0.f, 0.f, 0.f, 0.f};
    if (doOut) {
        const int orow = j * 16 + ln;      // natural rows: C m = out-col
        const float* s = Wout + orow * H;
        #pragma unroll
        for (int kk = 0; kk < 8; kk++) wo[kk] = pack8(s + kk * 32 + q * 8);
        #pragma unroll
        for (int r = 0; r < 4; r++) bor[r] = bout[j * 16 + q * 4 + r];
    }

    // ---- per-lane gate biases + cell state (per group) ----
    float gxr[4], creg;
    if (grp == 0) {
        #pragma unroll
        for (int r = 0; r < 4; r++) {
            u32 v = gxb0u[myb * 512 + ((r * 256 + mycol) >> 1)];
            gxr[r] = bs2f((unsigned short)((mycol & 1) ? (v >> 16) : (v & 0xFFFFu)));
        }
        creg = c0g[myb * H + mycol];
    } else {
        #pragma unroll
        for (int r = 0; r < 4; r++) gxr[r] = gxb1[r * 256 + mycol];
        creg = c1g[myb * H + mycol];
    }

    u64* A0 = h0B0 + bg * 2048;   // cluster slices: 16 rows x 128 pair-slots
    u64* A1 = h0B1 + bg * 2048;
    u64* B0 = h1B0 + bg * 2048;
    u64* B1 = h1B1 + bg * 2048;

    const int pubslot = ln * 128 + j * 8 + gwave * 2 + (q >> 1);   // even-q lanes
    const bool pubLane = ((q & 1) == 0);

    // ---- carried poll regs; preloop: grp0 snapshots A1 (prologue tag 0).
    //      grp1's first prefetch is issued at k=0 phase B (from B1, tag 1). ----
    u64 v[8];
    if (grp == 0) {
        #pragma unroll
        for (int i = 0; i < 8; i++) v[i] = sys_load_u64(A1 + i * 256 + gt);
    }

    for (int k = 0; k <= SEQ + 1; k++) {
        const int par = k & 1;

        // ================= phase A: staging =================
        if (grp == 0) {
            if (k <= SEQ) {
                const u64* P0 = par ? A0 : A1;
                bool ok = true;
                #pragma unroll
                for (int i = 0; i < 8; i++) ok = ok && ((u32)(v[i] >> 32) == (u32)k);
                int guard = 0;
                while (!ok && guard < 16384) {
                    ok = true;
                    #pragma unroll
                    for (int i = 0; i < 8; i++) v[i] = sys_load_u64(P0 + i * 256 + gt);
                    #pragma unroll
                    for (int i = 0; i < 8; i++) ok = ok && ((u32)(v[i] >> 32) == (u32)k);
                    guard++;
                }
                u32* dst = hs0[par];
                #pragma unroll
                for (int i = 0; i < 8; i++) { int s = i * 256 + gt; dst[(s >> 7) * 132 + (s & 127)] = (u32)v[i]; }
            }
        } else {
            if (k >= 1) {
                const u64* P1 = par ? B1 : B0;
                bool ok = true;
                #pragma unroll
                for (int i = 0; i < 8; i++) ok = ok && ((u32)(v[i] >> 32) == (u32)k);
                int guard = 0;
                while (!ok && guard < 16384) {
                    ok = true;
                    #pragma unroll
                    for (int i = 0; i < 8; i++) v[i] = sys_load_u64(P1 + i * 256 + gt);
                    #pragma unroll
                    for (int i = 0; i < 8; i++) ok = ok && ((u32)(v[i] >> 32) == (u32)k);
                    guard++;
                }
                u32* dst = hs1[par];
                #pragma unroll
                for (int i = 0; i < 8; i++) { int s = i * 256 + gt; dst[(s >> 7) * 132 + (s & 127)] = (u32)v[i]; }
            }
        }
        __syncthreads();                   // single barrier per iteration

        // ================= phase B: compute =================
        if (grp == 0) {
            // ---- layer 0, step k: h0(k) = lstm(gx0, h0(k-1)) ----
            if (k < SEQ) {
                bf16x8 hb0[8];
                const unsigned short* p0 = (const unsigned short*)hs0[par];
                #pragma unroll
                for (int kk = 0; kk < 8; kk++)
                    hb0[kk] = *(const bf16x8*)(p0 + ln * 264 + kk * 32 + q * 8);
                f32x4 acc = {0.f, 0.f, 0.f, 0.f};
                #pragma unroll
                for (int kk = 0; kk < 8; kk++)
                    acc = __builtin_amdgcn_mfma_f32_16x16x32_bf16(wfA[kk], hb0[kk], acc, 0, 0, 0);
                float i_ = sigm(acc[0] + gxr[0]);
                float f_ = sigm(acc[1] + gxr[1]);
                float g_ = tanhf_(acc[2] + gxr[2]);
                float o_ = sigm(acc[3] + gxr[3]);
                creg = f_ * creg + i_ * g_;
                int us = (int)(u32)(unsigned short)f2bs(o_ * tanhf_(creg));
                int other = __shfl_xor(us, 16);        // q <-> q^1 (col pair partner)
                u64* C0 = par ? A1 : A0;
                if (pubLane) {
                    u32 pa = (u32)us | ((u32)other << 16);
                    sys_store_u64(C0 + pubslot, ((u64)(u32)(k + 1) << 32) | (u64)pa);
                }
                // prefetch tag k+1 (after own publish -> own slots fresh);
                // other wgs' publishes at same phase -> occasional stale lines
                // fall back to the reload spin at next phase A.
                #pragma unroll
                for (int i = 0; i < 8; i++) v[i] = sys_load_u64(C0 + i * 256 + gt);
            }
        } else {
            bf16x8 hb1f[8];
            if (k >= 1) {
                const unsigned short* p1 = (const unsigned short*)hs1[par];
                #pragma unroll
                for (int kk = 0; kk < 8; kk++)
                    hb1f[kk] = *(const bf16x8*)(p1 + ln * 264 + kk * 32 + q * 8);
            }
            // ---- layer 1, step k-1: dual acc chains ----
            if (k >= 1 && k <= SEQ) {
                bf16x8 hb0[8];
                const unsigned short* p0 = (const unsigned short*)hs0[par];
                #pragma unroll
                for (int kk = 0; kk < 8; kk++)
                    hb0[kk] = *(const bf16x8*)(p0 + ln * 264 + kk * 32 + q * 8);
                f32x4 accA = {0.f, 0.f, 0.f, 0.f};
                f32x4 accB = {0.f, 0.f, 0.f, 0.f};
                #pragma unroll
                for (int kk = 0; kk < 8; kk++) {
                    accA = __builtin_amdgcn_mfma_f32_16x16x32_bf16(wfA[kk], hb0[kk], accA, 0, 0, 0);
                    accB = __builtin_amdgcn_mfma_f32_16x16x32_bf16(wfB[kk], hb1f[kk], accB, 0, 0, 0);
                }
                float i_ = sigm(accA[0] + accB[0] + gxr[0]);
                float f_ = sigm(accA[1] + accB[1] + gxr[1]);
                float g_ = tanhf_(accA[2] + accB[2] + gxr[2]);
                float o_ = sigm(accA[3] + accB[3] + gxr[3]);
                creg = f_ * creg + i_ * g_;
                int us = (int)(u32)(unsigned short)f2bs(o_ * tanhf_(creg));
                int other = __shfl_xor(us, 16);
                u64* C1 = par ? B0 : B1;
                if (pubLane) {
                    u32 pa = (u32)us | ((u32)other << 16);
                    sys_store_u64(C1 + pubslot, ((u64)(u32)(k + 1) << 32) | (u64)pa);
                }
            }
            // prefetch tag k+1 from C1(k) (k=0: B1 holds prologue tag 1)
            if (k <= SEQ) {
                const u64* C1p = par ? B0 : B1;
                #pragma unroll
                for (int i = 0; i < 8; i++) v[i] = sys_load_u64(C1p + i * 256 + gt);
            }
            // ---- out-projection, step k-2 (uses hb1f = h1(k-2)) ----
            if (doOut && k >= 2) {
                f32x4 acc;
                acc[0] = bor[0]; acc[1] = bor[1]; acc[2] = bor[2]; acc[3] = bor[3];
                #pragma unroll
                for (int kk = 0; kk < 8; kk++)
                    acc = __builtin_amdgcn_mfma_f32_16x16x32_bf16(wo[kk], hb1f[kk], acc, 0, 0, 0);
                *(f32x4*)&out[(bg * 16 + ln) * (SEQ * OUTD) + (k - 2) * OUTD + j * 16 + q * 4] = acc;
            }
        }
    }
}

extern "C" void kernel_launch(void* const* d_in, const int* in_sizes, int n_in,
                              void* d_out, int out_size, void* d_ws, size_t ws_size,
                              hipStream_t stream) {
    const float* z     = (const float*)d_in[0];
    const float* Whid  = (const float*)d_in[1];
    const float* bhid  = (const float*)d_in[2];
    const float* Wcell = (const float*)d_in[3];
    const float* bcell = (const float*)d_in[4];
    const float* Win   = (const float*)d_in[5];
    const float* bin   = (const float*)d_in[6];
    const float* Wih0  = (const float*)d_in[7];
    const float* Whh0  = (const float*)d_in[8];
    const float* bih0  = (const float*)d_in[9];
    const float* bhh0  = (const float*)d_in[10];
    const float* Wih1  = (const float*)d_in[11];
    const float* Whh1  = (const float*)d_in[12];
    const float* bih1  = (const float*)d_in[13];
    const float* bhh1  = (const float*)d_in[14];
    const float* Wout  = (const float*)d_in[15];
    const float* bout  = (const float*)d_in[16];
    float* out = (float*)d_out;

    // workspace: 2,101,248 B total (proven size)
    u32*   gxb0u = (u32*)d_ws;                   // [131072] bf16-pair gate biases
    float* gxb1  = (float*)(gxb0u + 131072);     // [1024]
    float* c0    = gxb1 + 1024;                  // [65536]
    float* c1    = c0 + 65536;                   // [65536]
    u64*   h0B0  = (u64*)(c1 + 65536);           // [32768] tagged pair-slots x4
    u64*   h0B1  = h0B0 + 32768;
    u64*   h1B0  = h0B1 + 32768;
    u64*   h1B1  = h1B0 + 32768;

    lstm_prologue_init<<<772, 256, 0, stream>>>(z, Whid, bhid, Wcell, bcell,
                                                bih1, bhh1, h0B1, h1B1, c0, c1, gxb1);
    lstm_prologue_gx0<<<dim3(2, 256), 256, 0, stream>>>(z, Win, bin, Wih0, bih0, bhh0, gxb0u);

    void* kargs[] = { (void*)&gxb0u, (void*)&gxb1, (void*)&c0, (void*)&c1,
                      (void*)&h0B0, (void*)&h0B1, (void*)&h1B0, (void*)&h1B1,
                      (void*)&Whh0, (void*)&Wih1, (void*)&Whh1, (void*)&Wout,
                      (void*)&bout, (void*)&out };
    hipError_t ce = hipLaunchCooperativeKernel((const void*)lstm_persistent,
                                               dim3(256), dim3(512), kargs, 0, stream);
    if (ce != hipSuccess) {
        lstm_persistent<<<256, 512, 0, stream>>>(gxb0u, gxb1, c0, c1,
                                                 h0B0, h0B1, h1B0, h1B1,
                                                 Whh0, Wih1, Whh1, Wout, bout, out);
    }
}

// Round 12
// 1507.172 us; speedup vs baseline: 1.6756x; 1.6756x over previous
//
#include <hip/hip_runtime.h>
#include <hip/hip_bf16.h>

#define LAT 128
#define H 256
#define OUTD 64
#define SEQ 512

typedef short bf16x8 __attribute__((ext_vector_type(8)));
typedef float f32x4  __attribute__((ext_vector_type(4)));
typedef unsigned long long u64;
typedef unsigned u32;

__device__ __forceinline__ float sigm(float x)  { return 1.f / (1.f + __expf(-x)); }
__device__ __forceinline__ float tanhf_(float x){ return 1.f - 2.f / (__expf(2.f * x) + 1.f); }

__device__ __forceinline__ short f2bs(float x) {
    __hip_bfloat16 b = __float2bfloat16(x);
    return *reinterpret_cast<short*>(&b);
}
__device__ __forceinline__ float bs2f(unsigned short h) {
    u32 b = ((u32)h) << 16;
    float f; __builtin_memcpy(&f, &b, 4); return f;
}
__device__ __forceinline__ u32 f2pair(float a, float b) {
    return ((u32)(unsigned short)f2bs(b) << 16) | (u32)(unsigned short)f2bs(a);
}
__device__ __forceinline__ bf16x8 pack8(const float* s) {
    bf16x8 v;
    v[0]=f2bs(s[0]); v[1]=f2bs(s[1]); v[2]=f2bs(s[2]); v[3]=f2bs(s[3]);
    v[4]=f2bs(s[4]); v[5]=f2bs(s[5]); v[6]=f2bs(s[6]); v[7]=f2bs(s[7]);
    return v;
}

// ---- Transport: AGENT scope. FINAL session-best configuration.
// 12-experiment ledger: R1 RMW publish (0) | R2 agent+per-line accept (--)
// | R3 merged polls (-) | R4 load-before-store vmcnt decoupling (-4.5%, KEPT)
// | R5 agent scope + L1 dual-acc (BEST) | R6 8-wg clusters (--) | R7
// consecutive-slot staging (--) | R8 early h0 prefetch (-) | R9 fused
// single-wg recurrence (--- 13x, weights must stay register-pinned) | R11
// wave-specialized split (--, lockstep barrier kills the overlap).
// The ~6330cy/step period is the latency-structural floor of a 512-step
// serial recurrence with two cross-CU handoffs/step among 16 producers.
__device__ __forceinline__ u64 sys_load_u64(const u64* p) {
    return __hip_atomic_load((u64*)p, __ATOMIC_RELAXED, __HIP_MEMORY_SCOPE_AGENT);
}
__device__ __forceinline__ void sys_store_u64(u64* p, u64 v) {
    __hip_atomic_store(p, v, __ATOMIC_RELAXED, __HIP_MEMORY_SCOPE_AGENT);
}

// ---------------- Prologue 1: tagged h-init, c-init, L1 bias ----
__global__ void lstm_prologue_init(const float* __restrict__ z,
                                   const float* __restrict__ Whid,
                                   const float* __restrict__ bhid,
                                   const float* __restrict__ Wcell,
                                   const float* __restrict__ bcell,
                                   const float* __restrict__ bih1,
                                   const float* __restrict__ bhh1,
                                   u64* __restrict__ h0B1,
                                   u64* __restrict__ h1B1,
                                   float* __restrict__ c0,
                                   float* __restrict__ c1,
                                   float* __restrict__ gxb1)
{
    int t = blockIdx.x * 256 + threadIdx.x;
    if (t < 65536) {                     // tagged hidden-init: 2 layers x 256 b x 128 pairs
        int layer = t >> 15;
        int tt = t & 32767;
        int b = tt >> 7, cp = tt & 127;
        int colA = layer * H + 2 * cp;
        const float* zr = z + b * LAT;
        const float* wA = Whid + colA * LAT;
        const float* wB = wA + LAT;
        float a0 = bhid[colA], a1 = bhid[colA + 1];
        for (int k = 0; k < LAT; k++) { float zv = zr[k]; a0 += zv * wA[k]; a1 += zv * wB[k]; }
        u64 v = ((u64)(u32)layer << 32) | (u64)f2pair(a0, a1);
        (layer ? h1B1 : h0B1)[b * 128 + cp] = v;
    } else if (t < 196608) {             // cell init: [256 x 512]
        int tt = t - 65536;
        int b = tt >> 9, col = tt & 511;
        const float* w  = Wcell + col * LAT;
        const float* zr = z + b * LAT;
        float acc = bcell[col];
        for (int k = 0; k < LAT; k++) acc += zr[k] * w[k];
        if (col < H) c0[b * H + col] = acc;
        else         c1[b * H + (col - H)] = acc;
    } else if (t < 197632) {             // layer-1 gate bias vector [1024]
        int g = t - 196608;
        gxb1[g] = bih1[g] + bhh1[g];
    }
}

// ---------------- Prologue 2: gx0 packed bf16 pairs ----
__global__ void lstm_prologue_gx0(const float* __restrict__ z,
                                  const float* __restrict__ Win,
                                  const float* __restrict__ bin,
                                  const float* __restrict__ Wih0,
                                  const float* __restrict__ bih0,
                                  const float* __restrict__ bhh0,
                                  u32* __restrict__ gxb0u)
{
    __shared__ float xs[H];
    const int b = blockIdx.y;
    const int tid = threadIdx.x;
    {
        const float* w  = Win + tid * LAT;
        const float* zr = z + b * LAT;
        float acc = bin[tid];
        for (int k = 0; k < LAT; k++) acc += zr[k] * w[k];
        xs[tid] = acc;
    }
    __syncthreads();
    const int cA = blockIdx.x * 512 + 2 * tid;
    const float* wA = Wih0 + cA * H;
    const float* wB = wA + H;
    float a0 = bih0[cA]     + bhh0[cA];
    float a1 = bih0[cA + 1] + bhh0[cA + 1];
    for (int k = 0; k < H; k++) { float xv = xs[k]; a0 += xv * wA[k]; a1 += xv * wB[k]; }
    gxb0u[b * 512 + blockIdx.x * 256 + tid] = f2pair(a0, a1);
}

// ---------------- Persistent kernel ----------------
// 256 wgs x 256 thr. Cluster bg = wg>>4, wg j = wg&15 owns 16 hidden cols.
// Two barriers, R0 poll positions, snapshot reload-all spins, agent scope,
// load-before-store vmcnt decoupling (R4), L1 dual accumulators (R5).
__global__ __launch_bounds__(256, 1)
void lstm_persistent(const u32* __restrict__ gxb0u, const float* __restrict__ gxb1,
                     const float* __restrict__ c0g, const float* __restrict__ c1g,
                     u64* __restrict__ h0B0, u64* __restrict__ h0B1,
                     u64* __restrict__ h1B0, u64* __restrict__ h1B1,
                     const float* __restrict__ Whh0, const float* __restrict__ Wih1,
                     const float* __restrict__ Whh1, const float* __restrict__ Wout,
                     const float* __restrict__ bout, float* __restrict__ out)
{
    const int wg = blockIdx.x;
    const int bg = wg >> 4;
    const int j  = wg & 15;
    const int tid  = threadIdx.x;
    const int wave = tid >> 6;
    const int q  = (tid >> 4) & 3;
    const int ln = tid & 15;
    const int mycol = j * 16 + wave * 4 + q;
    const int myb   = bg * 16 + ln;

    __shared__ u32 hs0[2][16 * 132];           // parity planes, row-major packed pairs
    __shared__ u32 hs1[2][16 * 132];

    // ---- A-frags: packed-gate weight rows (m = c*4 + g) ----
    bf16x8 wf[3][8];
    {
        const float* mats[3] = { Whh0, Wih1, Whh1 };
        const int arow = (ln & 3) * H + j * 16 + wave * 4 + (ln >> 2);
        #pragma unroll
        for (int mm = 0; mm < 3; mm++) {
            const float* s = mats[mm] + arow * H;
            #pragma unroll
            for (int kk = 0; kk < 8; kk++) wf[mm][kk] = pack8(s + kk * 32 + q * 8);
        }
    }
    const bool doOut = (j < 4) && (wave == 0);
    bf16x8 wo[8];
    float bor[4] = {0.f, 0.f, 0.f, 0.f};
    if (doOut) {
        const int orow = j * 16 + ln;          // natural rows: C m = out-col
        const float* s = Wout + orow * H;
        #pragma unroll
        for (int kk = 0; kk < 8; kk++) wo[kk] = pack8(s + kk * 32 + q * 8);
        #pragma unroll
        for (int r = 0; r < 4; r++) bor[r] = bout[j * 16 + q * 4 + r];
    }

    // ---- per-lane gate biases + cell state ----
    float gxr0[4], gxr1[4];
    #pragma unroll
    for (int r = 0; r < 4; r++) {
        u32 v = gxb0u[myb * 512 + ((r * 256 + mycol) >> 1)];
        gxr0[r] = bs2f((unsigned short)((mycol & 1) ? (v >> 16) : (v & 0xFFFFu)));
        gxr1[r] = gxb1[r * 256 + mycol];
    }
    float creg0 = c0g[myb * H + mycol];
    float creg1 = c1g[myb * H + mycol];

    u64* A0 = h0B0 + bg * 2048;   // cluster slices: 16 rows x 128 pair-slots
    u64* A1 = h0B1 + bg * 2048;
    u64* B0 = h1B0 + bg * 2048;
    u64* B1 = h1B1 + bg * 2048;

    const int pubslot = ln * 128 + j * 8 + wave * 2 + (q >> 1);   // even-q lanes
    const bool pubLane = ((q & 1) == 0);

    // ---- carried h0 poll regs; preloop: k=0 snapshot from A1 (prologue tag 0) ----
    u64 v0[8];
    #pragma unroll
    for (int i = 0; i < 8; i++) v0[i] = sys_load_u64(A1 + i * 256 + tid);

    for (int k = 0; k <= SEQ + 1; k++) {
        const u64* P1 = (k & 1) ? B1 : B0;  u64* C1 = (k & 1) ? B0 : B1;
        u64* C0 = (k & 1) ? A1 : A0;
        const int par = k & 1;

        // ---- TOP staging: h0 (carried snapshot check; reload-all fallback) ----
        if (k <= SEQ) {
            const u64* P0 = (k & 1) ? A0 : A1;
            bool ok = true;
            #pragma unroll
            for (int i = 0; i < 8; i++) ok = ok && ((u32)(v0[i] >> 32) == (u32)k);
            int guard = 0;
            while (!ok && guard < 16384) {
                ok = true;
                #pragma unroll
                for (int i = 0; i < 8; i++) v0[i] = sys_load_u64(P0 + i * 256 + tid);
                #pragma unroll
                for (int i = 0; i < 8; i++) ok = ok && ((u32)(v0[i] >> 32) == (u32)k);
                guard++;
            }
            u32* dst = hs0[par];
            #pragma unroll
            for (int i = 0; i < 8; i++) { int s = i * 256 + tid; dst[(s >> 7) * 132 + (s & 127)] = (u32)v0[i]; }
        }
        __syncthreads();                       // B1

        // ---- h0 B-frags (batch row ln) ----
        bf16x8 hb0[8];
        {
            const unsigned short* b0p = (const unsigned short*)hs0[par];
            #pragma unroll
            for (int kk = 0; kk < 8; kk++)
                hb0[kk] = *(const bf16x8*)(b0p + ln * 264 + kk * 32 + q * 8);
        }

        // ---- issue h1 tag-k poll loads NOW (~0.35T cover to the MID check;
        //      older than the L0 publish store -> check excludes store ack) ----
        u64 v1[8];
        if (k >= 1) {
            #pragma unroll
            for (int i = 0; i < 8; i++) v1[i] = sys_load_u64(P1 + i * 256 + tid);
        }
        __builtin_amdgcn_sched_barrier(0);     // pin: loads issued before L0 block

        // ---- layer 0, step k: gates in acc, publish from regs ----
        if (k < SEQ) {
            f32x4 acc = {0.f, 0.f, 0.f, 0.f};
            #pragma unroll
            for (int kk = 0; kk < 8; kk++)
                acc = __builtin_amdgcn_mfma_f32_16x16x32_bf16(wf[0][kk], hb0[kk], acc, 0, 0, 0);
            float i_ = sigm(acc[0] + gxr0[0]);
            float f_ = sigm(acc[1] + gxr0[1]);
            float g_ = tanhf_(acc[2] + gxr0[2]);
            float o_ = sigm(acc[3] + gxr0[3]);
            creg0 = f_ * creg0 + i_ * g_;
            int us = (int)(u32)(unsigned short)f2bs(o_ * tanhf_(creg0));
            int other = __shfl_xor(us, 16);    // q <-> q^1 (col pair partner)
            if (pubLane) {
                u32 pa = (u32)us | ((u32)other << 16);
                sys_store_u64(C0 + pubslot, ((u64)(u32)(k + 1) << 32) | (u64)pa);
            }
        }

        // ---- MID staging: h1 (check prefetched snapshot; reload-all fallback) ----
        if (k >= 1) {
            bool ok = true;
            #pragma unroll
            for (int i = 0; i < 8; i++) ok = ok && ((u32)(v1[i] >> 32) == (u32)k);
            int guard = 0;
            while (!ok && guard < 16384) {
                ok = true;
                #pragma unroll
                for (int i = 0; i < 8; i++) v1[i] = sys_load_u64(P1 + i * 256 + tid);
                #pragma unroll
                for (int i = 0; i < 8; i++) ok = ok && ((u32)(v1[i] >> 32) == (u32)k);
                guard++;
            }
            u32* dst = hs1[par];
            #pragma unroll
            for (int i = 0; i < 8; i++) { int s = i * 256 + tid; dst[(s >> 7) * 132 + (s & 127)] = (u32)v1[i]; }
        }
        __syncthreads();                       // B2

        // ---- h1 B-frags ----
        bf16x8 hb1[8];
        {
            const unsigned short* b1p = (const unsigned short*)hs1[par];
            #pragma unroll
            for (int kk = 0; kk < 8; kk++)
                hb1[kk] = *(const bf16x8*)(b1p + ln * 264 + kk * 32 + q * 8);
        }

        // ---- layer 1, step k-1: two independent acc chains (8+8 pipelined) ----
        u32 pa1 = 0; bool pub1 = false;
        if (k >= 1 && k <= SEQ) {
            f32x4 accA = {0.f, 0.f, 0.f, 0.f};
            f32x4 accB = {0.f, 0.f, 0.f, 0.f};
            #pragma unroll
            for (int kk = 0; kk < 8; kk++) {
                accA = __builtin_amdgcn_mfma_f32_16x16x32_bf16(wf[1][kk], hb0[kk], accA, 0, 0, 0);
                accB = __builtin_amdgcn_mfma_f32_16x16x32_bf16(wf[2][kk], hb1[kk], accB, 0, 0, 0);
            }
            float i_ = sigm(accA[0] + accB[0] + gxr1[0]);
            float f_ = sigm(accA[1] + accB[1] + gxr1[1]);
            float g_ = tanhf_(accA[2] + accB[2] + gxr1[2]);
            float o_ = sigm(accA[3] + accB[3] + gxr1[3]);
            creg1 = f_ * creg1 + i_ * g_;
            int us = (int)(u32)(unsigned short)f2bs(o_ * tanhf_(creg1));
            int other = __shfl_xor(us, 16);
            pa1 = (u32)us | ((u32)other << 16);
            pub1 = pubLane;
        }

        // ---- LATE h0 prefetch for k+1 (published at ~0.4T this iter by all
        //      wgs). Issued BEFORE the L1 publish store so the top-of-(k+1)
        //      check's counted vmcnt excludes the store ack. ----
        if (k < SEQ) {
            #pragma unroll
            for (int i = 0; i < 8; i++) v0[i] = sys_load_u64(C0 + i * 256 + tid);
        }
        __builtin_amdgcn_sched_barrier(0);     // pin: prefetch before publish store

        // ---- layer-1 publish (store younger than all poll loads) ----
        if (pub1) {
            sys_store_u64(C1 + pubslot, ((u64)(u32)(k + 1) << 32) | (u64)pa1);
        }

        // ---- output projection, step k-2 (reuses hb1 = h1_{k-2}); f32x4 store ----
        if (k >= 2 && doOut) {
            f32x4 acc = {0.f, 0.f, 0.f, 0.f};
            #pragma unroll
            for (int kk = 0; kk < 8; kk++)
                acc = __builtin_amdgcn_mfma_f32_16x16x32_bf16(wo[kk], hb1[kk], acc, 0, 0, 0);
            f32x4 res;
            #pragma unroll
            for (int r = 0; r < 4; r++) res[r] = acc[r] + bor[r];
            *(f32x4*)&out[(bg * 16 + ln) * (SEQ * OUTD) + (k - 2) * OUTD + j * 16 + q * 4] = res;
        }
    }
}

extern "C" void kernel_launch(void* const* d_in, const int* in_sizes, int n_in,
                              void* d_out, int out_size, void* d_ws, size_t ws_size,
                              hipStream_t stream) {
    const float* z     = (const float*)d_in[0];
    const float* Whid  = (const float*)d_in[1];
    const float* bhid  = (const float*)d_in[2];
    const float* Wcell = (const float*)d_in[3];
    const float* bcell = (const float*)d_in[4];
    const float* Win   = (const float*)d_in[5];
    const float* bin   = (const float*)d_in[6];
    const float* Wih0  = (const float*)d_in[7];
    const float* Whh0  = (const float*)d_in[8];
    const float* bih0  = (const float*)d_in[9];
    const float* bhh0  = (const float*)d_in[10];
    const float* Wih1  = (const float*)d_in[11];
    const float* Whh1  = (const float*)d_in[12];
    const float* bih1  = (const float*)d_in[13];
    const float* bhh1  = (const float*)d_in[14];
    const float* Wout  = (const float*)d_in[15];
    const float* bout  = (const float*)d_in[16];
    float* out = (float*)d_out;

    // workspace: 2,101,248 B total (proven size)
    u32*   gxb0u = (u32*)d_ws;                   // [131072] bf16-pair gate biases
    float* gxb1  = (float*)(gxb0u + 131072);     // [1024]
    float* c0    = gxb1 + 1024;                  // [65536]
    float* c1    = c0 + 65536;                   // [65536]
    u64*   h0B0  = (u64*)(c1 + 65536);           // [32768] tagged pair-slots x4
    u64*   h0B1  = h0B0 + 32768;
    u64*   h1B0  = h0B1 + 32768;
    u64*   h1B1  = h1B0 + 32768;

    lstm_prologue_init<<<772, 256, 0, stream>>>(z, Whid, bhid, Wcell, bcell,
                                                bih1, bhh1, h0B1, h1B1, c0, c1, gxb1);
    lstm_prologue_gx0<<<dim3(2, 256), 256, 0, stream>>>(z, Win, bin, Wih0, bih0, bhh0, gxb0u);

    void* kargs[] = { (void*)&gxb0u, (void*)&gxb1, (void*)&c0, (void*)&c1,
                      (void*)&h0B0, (void*)&h0B1, (void*)&h1B0, (void*)&h1B1,
                      (void*)&Whh0, (void*)&Wih1, (void*)&Whh1, (void*)&Wout,
                      (void*)&bout, (void*)&out };
    hipError_t ce = hipLaunchCooperativeKernel((const void*)lstm_persistent,
                                               dim3(256), dim3(256), kargs, 0, stream);
    if (ce != hipSuccess) {
        lstm_persistent<<<256, 256, 0, stream>>>(gxb0u, gxb1, c0, c1,
                                                 h0B0, h0B1, h1B0, h1B1,
                                                 Whh0, Wih1, Whh1, Wout, bout, out);
    }
}